// Round 5
// baseline (279.685 us; speedup 1.0000x reference)
//
#include <hip/hip_runtime.h>
#include <hip/hip_bf16.h>

#define HH   64
#define H2   128
#define VOC  64
#define LSEQ 2048

typedef float f2 __attribute__((ext_vector_type(2)));

// ---------------------------------------------------------------------------
// Kernel 1: collapse embed -> FFN -> LN -> {kn, v, q} projections into
// per-token tables (VOCAB=64 entries of H=64 floats each).  (unchanged)
// ---------------------------------------------------------------------------
__global__ __launch_bounds__(128) void build_tables(
    const float* __restrict__ embed, const float* __restrict__ w1, const float* __restrict__ b1,
    const float* __restrict__ w2, const float* __restrict__ b2,
    const float* __restrict__ ln_g, const float* __restrict__ ln_b,
    const float* __restrict__ wk, const float* __restrict__ wv, const float* __restrict__ wq,
    float* __restrict__ kn_t, float* __restrict__ v_t, float* __restrict__ q_t)
{
    const int tok = blockIdx.x;
    const int tid = threadIdx.x;
    __shared__ float e_lds[HH];
    __shared__ float h_lds[H2];
    __shared__ float hs_lds[HH];

    if (tid < HH) e_lds[tid] = embed[tok * HH + tid];
    __syncthreads();

    {
        float s = b1[tid];
        #pragma unroll 8
        for (int i = 0; i < HH; ++i) s = fmaf(e_lds[i], w1[i * H2 + tid], s);
        h_lds[tid] = fmaxf(s, 0.f);
    }
    __syncthreads();

    if (tid < HH) {
        float f = b2[tid];
        #pragma unroll 8
        for (int j = 0; j < H2; ++j) f = fmaf(h_lds[j], w2[j * HH + tid], f);
        float x = e_lds[tid] + f;
        float sum = x, sq = x * x;
        #pragma unroll
        for (int m = 1; m < 64; m <<= 1) { sum += __shfl_xor(sum, m); sq += __shfl_xor(sq, m); }
        float mu  = sum * (1.f / HH);
        float var = sq * (1.f / HH) - mu * mu;
        hs_lds[tid] = (x - mu) * rsqrtf(var + 1e-5f) * ln_g[tid] + ln_b[tid];
    }
    __syncthreads();

    if (tid < HH) {
        float k = 0.f, v = 0.f, q = 0.f;
        #pragma unroll 8
        for (int j = 0; j < HH; ++j) {
            float h = hs_lds[j];
            k = fmaf(h, wk[j * HH + tid], k);
            v = fmaf(h, wv[j * HH + tid], v);
            q = fmaf(h, wq[j * HH + tid], q);
        }
        float kk = k * k;
        #pragma unroll
        for (int m = 1; m < 64; m <<= 1) kk += __shfl_xor(kk, m);
        float kn = k / fmaxf(sqrtf(kk), 1e-12f);
        kn_t[tok * HH + tid] = kn;
        v_t [tok * HH + tid] = v;
        q_t [tok * HH + tid] = q;
    }
}

// ---------------------------------------------------------------------------
// Kernel 1b: W[a][b] = kn_a . kn_b  for all 64x64 token pairs (16 KB table).
// Lets the scan replace the k_t.k_{t+1} dot with an LDS lookup.
// ---------------------------------------------------------------------------
__global__ __launch_bounds__(64) void build_w(
    const float* __restrict__ kn_t, float* __restrict__ w_t)
{
    const int a = blockIdx.x, b = threadIdx.x;
    __shared__ float ka[HH];
    ka[b] = kn_t[a * HH + b];
    __syncthreads();
    const float4* kav = (const float4*)ka;
    const float4* kbv = (const float4*)(kn_t + b * HH);
    float4 s = {0.f, 0.f, 0.f, 0.f};
    #pragma unroll
    for (int j = 0; j < 16; ++j) {
        float4 x = kav[j], y = kbv[j];
        s.x = fmaf(x.x, y.x, s.x); s.y = fmaf(x.y, y.y, s.y);
        s.z = fmaf(x.z, y.z, s.z); s.w = fmaf(x.w, y.w, s.w);
    }
    w_t[a * VOC + b] = (s.x + s.y) + (s.z + s.w);
}

// ---------------------------------------------------------------------------
// Kernel 2: per-batch scan, lag-1 WY pipelined:
//   vp_{t+1} = M_{t-1}.k_{t+1} + d_t * W[tok_t][tok_{t+1}]
//   d_{t+1}  = v_{t+1} - vp_{t+1};   M <- M + d_t k_t^T  (deferred update)
// The M.k dot no longer depends on the newest d -> serial chain is ~1 fmaf.
// 4-deep rotating K register buffers, tokens/v/w prefetched 2 iters ahead.
// ---------------------------------------------------------------------------
__device__ __forceinline__ float quad_sum(float p) {
    int q = __builtin_amdgcn_mov_dpp(__builtin_bit_cast(int, p), 0xB1, 0xF, 0xF, true);
    p += __builtin_bit_cast(float, q);
    q = __builtin_amdgcn_mov_dpp(__builtin_bit_cast(int, p), 0x4E, 0xF, 0xF, true);
    p += __builtin_bit_cast(float, q);
    return p;
}

__device__ __forceinline__ void loadK(f2 K[8], const float* __restrict__ src) {
    const float4* p = (const float4*)src;
    float4 x = p[0], y = p[1], z = p[2], w = p[3];
    K[0] = (f2){x.x, x.y}; K[1] = (f2){x.z, x.w};
    K[2] = (f2){y.x, y.y}; K[3] = (f2){y.z, y.w};
    K[4] = (f2){z.x, z.y}; K[5] = (f2){z.z, z.w};
    K[6] = (f2){w.x, w.y}; K[7] = (f2){w.z, w.w};
}

#define ITER(U)                                                              \
{                                                                            \
    const int pb = ((U) + 3) & 3;                                            \
    const int cb = ((U) + 1) & 3;                                            \
    /* prefetch materials for step nn+3 (addresses from tokens loaded >=2 iters ago) */ \
    loadK(Kb[pb], &kn_lds[tk3 * HH + j0]);                                   \
    vb[pb] = v_lds[tk3 * HH + i];                                            \
    wb[pb] = w_lds[tk2 * VOC + tk3];                                         \
    const int tk5v = seq_lds[nn + 5];                                        \
    /* raw = M_{n-1} . k_{n+1} : independent of dP */                        \
    f2 c0 = M2[0] * Kb[cb][0] + M2[4] * Kb[cb][4];                           \
    f2 c1 = M2[1] * Kb[cb][1] + M2[5] * Kb[cb][5];                           \
    f2 c2 = M2[2] * Kb[cb][2] + M2[6] * Kb[cb][6];                           \
    f2 c3 = M2[3] * Kb[cb][3] + M2[7] * Kb[cb][7];                           \
    /* deferred rank-1 update: M <- M + d_n k_n^T (uses OLD dP) */           \
    {                                                                        \
        f2 d2 = {dP, dP};                                                    \
        _Pragma("unroll")                                                    \
        for (int m8 = 0; m8 < 8; ++m8) M2[m8] += d2 * Kb[(U) & 3][m8];       \
    }                                                                        \
    f2 cc = (c0 + c1) + (c2 + c3);                                           \
    float rawp = quad_sum(cc[0] + cc[1]);                                    \
    float dN = vb[cb] - fmaf(dP, wb[cb], rawp);                              \
    dP = dN;                                                                 \
    tk2 = tk3; tk3 = tk4; tk4 = tk5v;                                        \
    ++nn;                                                                    \
}

__global__ __launch_bounds__(256) void delta_scan(
    const int* __restrict__ seq,
    const float* __restrict__ kn_t, const float* __restrict__ v_t, const float* __restrict__ q_t,
    const float* __restrict__ w_t,
    const float* __restrict__ wrp, const float* __restrict__ brp,
    const float* __restrict__ wout, const float* __restrict__ bout,
    float* __restrict__ out)
{
    __shared__ __align__(64) float kn_lds[VOC * HH];
    __shared__ __align__(64) float v_lds[VOC * HH];
    __shared__ __align__(64) float w_lds[VOC * VOC];
    __shared__ __align__(16) int   seq_lds[LSEQ + 8];
    __shared__ float r_lds[HH];
    __shared__ float t_lds[HH];

    const int b   = blockIdx.x;
    const int tid = threadIdx.x;

    // cooperative staging: kn/v/W tables (3 x 16KB) + token row (8KB)
    {
        const float4* s1 = (const float4*)kn_t; float4* d1 = (float4*)kn_lds;
        const float4* s2 = (const float4*)v_t;  float4* d2 = (float4*)v_lds;
        const float4* s4 = (const float4*)w_t;  float4* d4 = (float4*)w_lds;
        #pragma unroll
        for (int r = 0; r < 4; ++r) {
            d1[tid + 256 * r] = s1[tid + 256 * r];
            d2[tid + 256 * r] = s2[tid + 256 * r];
            d4[tid + 256 * r] = s4[tid + 256 * r];
        }
        const int4* s3 = (const int4*)(seq + (long)b * LSEQ);
        int4* d3 = (int4*)seq_lds;
        #pragma unroll
        for (int r = 0; r < 2; ++r) d3[tid + 256 * r] = s3[tid + 256 * r];
        if (tid < 8) seq_lds[LSEQ + tid] = 0;   // pad: loop prefetch reads up to [2050]
    }
    __syncthreads();

    const int i  = tid >> 2;          // M row this thread contributes to
    const int j0 = (tid & 3) * 16;    // column slice base

    f2 M2[8];
    #pragma unroll
    for (int n = 0; n < 8; ++n) M2[n] = (f2){0.f, 0.f};

    f2 Kb[4][8];
    float vb[4], wb[4];

    // prologue: pipeline fill.  M2 = M_{-1} = 0, pending (d_0 = v_0, K_0).
    const int t0 = seq_lds[0], t1 = seq_lds[1], t2 = seq_lds[2];
    int tk2 = t2, tk3 = seq_lds[3], tk4 = seq_lds[4];
    loadK(Kb[0], &kn_lds[t0 * HH + j0]);
    loadK(Kb[1], &kn_lds[t1 * HH + j0]);
    loadK(Kb[2], &kn_lds[t2 * HH + j0]);
    float dP = v_lds[t0 * HH + i];
    vb[1] = v_lds[t1 * HH + i];
    vb[2] = v_lds[t2 * HH + i];
    wb[1] = w_lds[t0 * VOC + t1];
    wb[2] = w_lds[t1 * VOC + t2];

    // iters n = 0..2045 process steps 1..2046
    int nn = 0;
    for (int g = 0; g < 511; ++g) {
        ITER(0) ITER(1) ITER(2) ITER(3)
    }
    ITER(0) ITER(1)

    // apply final pending update: M = M_2046-state; K_2046 lives in slot 2046&3 = 2
    {
        f2 d2 = {dP, dP};
        #pragma unroll
        for (int m8 = 0; m8 < 8; ++m8) M2[m8] += d2 * Kb[2][m8];
    }

    // r_i = sum_j M[i][j] * q_j  with q = q_table[last token]
    {
        const int qtok = seq_lds[LSEQ - 1];
        const float* qrow = q_t + (long)qtok * HH + j0;
        f2 a0 = (f2){0.f, 0.f}, a1 = (f2){0.f, 0.f};
        #pragma unroll
        for (int n = 0; n < 4; ++n) {
            f2 q0 = (f2){qrow[2*n],     qrow[2*n + 1]};
            f2 q1 = (f2){qrow[2*n + 8], qrow[2*n + 9]};
            a0 += M2[n]     * q0;
            a1 += M2[n + 4] * q1;
        }
        f2 a = a0 + a1;
        float p = quad_sum(a[0] + a[1]);
        if ((tid & 3) == 0) r_lds[i] = p;
    }
    __syncthreads();

    // t = r @ wrp + brp
    if (tid < HH) {
        float s = brp[tid];
        #pragma unroll 8
        for (int ii = 0; ii < HH; ++ii) s = fmaf(r_lds[ii], wrp[ii * HH + tid], s);
        t_lds[tid] = s;
    }
    __syncthreads();

    // out = t @ wout + bout
    if (tid < HH) {
        float s = bout[tid];
        #pragma unroll 8
        for (int h = 0; h < HH; ++h) s = fmaf(t_lds[h], wout[h * VOC + tid], s);
        out[(long)b * VOC + tid] = s;
    }
}

extern "C" void kernel_launch(void* const* d_in, const int* in_sizes, int n_in,
                              void* d_out, int out_size, void* d_ws, size_t ws_size,
                              hipStream_t stream)
{
    const int*   seq   = (const int*)  d_in[0];
    const float* embed = (const float*)d_in[1];
    const float* w1    = (const float*)d_in[2];
    const float* b1    = (const float*)d_in[3];
    const float* w2    = (const float*)d_in[4];
    const float* b2    = (const float*)d_in[5];
    const float* ln_g  = (const float*)d_in[6];
    const float* ln_b  = (const float*)d_in[7];
    const float* wk    = (const float*)d_in[8];
    const float* wv    = (const float*)d_in[9];
    const float* wq    = (const float*)d_in[10];
    const float* wrp   = (const float*)d_in[11];
    const float* brp   = (const float*)d_in[12];
    const float* wout  = (const float*)d_in[13];
    const float* bout  = (const float*)d_in[14];
    float* out = (float*)d_out;

    float* kn_t = (float*)d_ws;
    float* v_t  = kn_t + VOC * HH;
    float* q_t  = v_t  + VOC * HH;
    float* w_t  = q_t  + VOC * HH;

    const int B = in_sizes[0] / LSEQ;   // 256

    hipLaunchKernelGGL(build_tables, dim3(VOC), dim3(H2), 0, stream,
                       embed, w1, b1, w2, b2, ln_g, ln_b, wk, wv, wq,
                       kn_t, v_t, q_t);
    hipLaunchKernelGGL(build_w, dim3(VOC), dim3(HH), 0, stream, kn_t, w_t);
    hipLaunchKernelGGL(delta_scan, dim3(B), dim3(256), 0, stream,
                       seq, kn_t, v_t, q_t, w_t, wrp, brp, wout, bout, out);
}

// Round 6
// 252.875 us; speedup vs baseline: 1.1060x; 1.1060x over previous
//
#include <hip/hip_runtime.h>
#include <hip/hip_bf16.h>

#define HH   64
#define H2   128
#define VOC  64
#define LSEQ 2048

typedef float f2 __attribute__((ext_vector_type(2)));

// ---------------------------------------------------------------------------
// Kernel 1: collapse embed -> FFN -> LN -> {kn, v, q} projections into
// per-token tables (VOCAB=64 entries of H=64 floats each).  (unchanged)
// ---------------------------------------------------------------------------
__global__ __launch_bounds__(128) void build_tables(
    const float* __restrict__ embed, const float* __restrict__ w1, const float* __restrict__ b1,
    const float* __restrict__ w2, const float* __restrict__ b2,
    const float* __restrict__ ln_g, const float* __restrict__ ln_b,
    const float* __restrict__ wk, const float* __restrict__ wv, const float* __restrict__ wq,
    float* __restrict__ kn_t, float* __restrict__ v_t, float* __restrict__ q_t)
{
    const int tok = blockIdx.x;
    const int tid = threadIdx.x;
    __shared__ float e_lds[HH];
    __shared__ float h_lds[H2];
    __shared__ float hs_lds[HH];

    if (tid < HH) e_lds[tid] = embed[tok * HH + tid];
    __syncthreads();

    {
        float s = b1[tid];
        #pragma unroll 8
        for (int i = 0; i < HH; ++i) s = fmaf(e_lds[i], w1[i * H2 + tid], s);
        h_lds[tid] = fmaxf(s, 0.f);
    }
    __syncthreads();

    if (tid < HH) {
        float f = b2[tid];
        #pragma unroll 8
        for (int j = 0; j < H2; ++j) f = fmaf(h_lds[j], w2[j * HH + tid], f);
        float x = e_lds[tid] + f;
        float sum = x, sq = x * x;
        #pragma unroll
        for (int m = 1; m < 64; m <<= 1) { sum += __shfl_xor(sum, m); sq += __shfl_xor(sq, m); }
        float mu  = sum * (1.f / HH);
        float var = sq * (1.f / HH) - mu * mu;
        hs_lds[tid] = (x - mu) * rsqrtf(var + 1e-5f) * ln_g[tid] + ln_b[tid];
    }
    __syncthreads();

    if (tid < HH) {
        float k = 0.f, v = 0.f, q = 0.f;
        #pragma unroll 8
        for (int j = 0; j < HH; ++j) {
            float h = hs_lds[j];
            k = fmaf(h, wk[j * HH + tid], k);
            v = fmaf(h, wv[j * HH + tid], v);
            q = fmaf(h, wq[j * HH + tid], q);
        }
        float kk = k * k;
        #pragma unroll
        for (int m = 1; m < 64; m <<= 1) kk += __shfl_xor(kk, m);
        float kn = k / fmaxf(sqrtf(kk), 1e-12f);
        kn_t[tok * HH + tid] = kn;
        v_t [tok * HH + tid] = v;
        q_t [tok * HH + tid] = q;
    }
}

// ---------------------------------------------------------------------------
// Kernel 1b: W[a][b] = kn_a . kn_b  (64x64 token-pair dot table, unchanged)
// ---------------------------------------------------------------------------
__global__ __launch_bounds__(64) void build_w(
    const float* __restrict__ kn_t, float* __restrict__ w_t)
{
    const int a = blockIdx.x, b = threadIdx.x;
    __shared__ float ka[HH];
    ka[b] = kn_t[a * HH + b];
    __syncthreads();
    const float4* kav = (const float4*)ka;
    const float4* kbv = (const float4*)(kn_t + b * HH);
    float4 s = {0.f, 0.f, 0.f, 0.f};
    #pragma unroll
    for (int j = 0; j < 16; ++j) {
        float4 x = kav[j], y = kbv[j];
        s.x = fmaf(x.x, y.x, s.x); s.y = fmaf(x.y, y.y, s.y);
        s.z = fmaf(x.z, y.z, s.z); s.w = fmaf(x.w, y.w, s.w);
    }
    w_t[a * VOC + b] = (s.x + s.y) + (s.z + s.w);
}

// ---------------------------------------------------------------------------
// Kernel 2: lag-1 WY scan, 8-deep software pipeline.
//   iter n:  rawp = M_{n-1}.k_{n+1};  M += d_n k_n^T;
//            d_{n+1} = v_{n+1} - (rawp + d_n * W[tok_n][tok_{n+1}])
// Slot for step m is m&7.  Prefetch distance: K/v/w loaded 6 iters before
// use; tokens held in a 10-deep queue refilled 8/group (slack >= 8 iters).
// All buffer indices are compile-time constants (8x unrolled groups).
// ---------------------------------------------------------------------------
__device__ __forceinline__ float quad_sum(float p) {
    int q = __builtin_amdgcn_mov_dpp(__builtin_bit_cast(int, p), 0xB1, 0xF, 0xF, true);
    p += __builtin_bit_cast(float, q);
    q = __builtin_amdgcn_mov_dpp(__builtin_bit_cast(int, p), 0x4E, 0xF, 0xF, true);
    p += __builtin_bit_cast(float, q);
    return p;
}

__device__ __forceinline__ void loadK(f2 K[8], const float* __restrict__ src) {
    const float4* p = (const float4*)src;
    float4 x = p[0], y = p[1], z = p[2], w = p[3];
    K[0] = (f2){x.x, x.y}; K[1] = (f2){x.z, x.w};
    K[2] = (f2){y.x, y.y}; K[3] = (f2){y.z, y.w};
    K[4] = (f2){z.x, z.y}; K[5] = (f2){z.z, z.w};
    K[6] = (f2){w.x, w.y}; K[7] = (f2){w.z, w.w};
}

// BODY(u): one scan iteration with n ≡ u (mod 8).
//  - prefetch K/v/w for step n+6 into slot (u+6)&7 using tokens T[u],T[u+1]
//  - consume slot (u+1)&7 (k_{n+1}, v_{n+1}, W) and slot u (k_n, update)
#define BODY(u)                                                              \
{                                                                            \
    const int sp = ((u) + 6) & 7;                                            \
    const int sc = ((u) + 1) & 7;                                            \
    const int th = T[(u) + 1];                                               \
    const int tl = T[(u)];                                                   \
    loadK(Kb[sp], &kn_lds[th * HH + j0]);                                    \
    vb[sp] = v_lds[th * HH + i];                                             \
    wb[sp] = w_lds[tl * VOC + th];                                           \
    /* rawp = M_{n-1} . k_{n+1} (reads M2 before the update below) */        \
    f2 c0 = M2[0] * Kb[sc][0] + M2[4] * Kb[sc][4];                           \
    f2 c1 = M2[1] * Kb[sc][1] + M2[5] * Kb[sc][5];                           \
    f2 c2 = M2[2] * Kb[sc][2] + M2[6] * Kb[sc][6];                           \
    f2 c3 = M2[3] * Kb[sc][3] + M2[7] * Kb[sc][7];                           \
    /* deferred rank-1 update with OLD dP: M <- M + d_n k_n^T */             \
    {                                                                        \
        f2 d2 = {dP, dP};                                                    \
        _Pragma("unroll")                                                    \
        for (int m8 = 0; m8 < 8; ++m8) M2[m8] += d2 * Kb[(u)][m8];           \
    }                                                                        \
    f2 cc = (c0 + c1) + (c2 + c3);                                           \
    float rawp = quad_sum(cc[0] + cc[1]);                                    \
    dP = vb[sc] - fmaf(dP, wb[sc], rawp);                                    \
}

__global__ __launch_bounds__(256) void delta_scan(
    const int* __restrict__ seq,
    const float* __restrict__ kn_t, const float* __restrict__ v_t, const float* __restrict__ q_t,
    const float* __restrict__ w_t,
    const float* __restrict__ wrp, const float* __restrict__ brp,
    const float* __restrict__ wout, const float* __restrict__ bout,
    float* __restrict__ out)
{
    __shared__ __align__(64) float kn_lds[VOC * HH];
    __shared__ __align__(64) float v_lds[VOC * HH];
    __shared__ __align__(64) float w_lds[VOC * VOC];
    __shared__ __align__(16) int   seq_lds[LSEQ + 8];
    __shared__ float r_lds[HH];
    __shared__ float t_lds[HH];

    const int b   = blockIdx.x;
    const int tid = threadIdx.x;

    // cooperative staging: kn/v/W tables (3 x 16KB) + token row (8KB)
    {
        const float4* s1 = (const float4*)kn_t; float4* d1 = (float4*)kn_lds;
        const float4* s2 = (const float4*)v_t;  float4* d2 = (float4*)v_lds;
        const float4* s4 = (const float4*)w_t;  float4* d4 = (float4*)w_lds;
        #pragma unroll
        for (int r = 0; r < 4; ++r) {
            d1[tid + 256 * r] = s1[tid + 256 * r];
            d2[tid + 256 * r] = s2[tid + 256 * r];
            d4[tid + 256 * r] = s4[tid + 256 * r];
        }
        const int4* s3 = (const int4*)(seq + (long)b * LSEQ);
        int4* d3 = (int4*)seq_lds;
        #pragma unroll
        for (int r = 0; r < 2; ++r) d3[tid + 256 * r] = s3[tid + 256 * r];
        if (tid < 8) seq_lds[LSEQ + tid] = 0;   // pads: reads reach [2054]
    }
    __syncthreads();

    const int i  = tid >> 2;          // M row this thread contributes to
    const int j0 = (tid & 3) * 16;    // column slice base

    f2 M2[8];
    #pragma unroll
    for (int n = 0; n < 8; ++n) M2[n] = (f2){0.f, 0.f};

    f2 Kb[8][8];
    float vb[8], wb[8];
    int T[10], N[8];

    // ---- prologue: fill slots for steps 0..5, token queue for steps 5..14.
    {
        const int p0 = seq_lds[0], p1 = seq_lds[1], p2 = seq_lds[2];
        const int p3 = seq_lds[3], p4 = seq_lds[4], p5 = seq_lds[5];
        loadK(Kb[0], &kn_lds[p0 * HH + j0]);
        loadK(Kb[1], &kn_lds[p1 * HH + j0]);
        loadK(Kb[2], &kn_lds[p2 * HH + j0]);
        loadK(Kb[3], &kn_lds[p3 * HH + j0]);
        loadK(Kb[4], &kn_lds[p4 * HH + j0]);
        loadK(Kb[5], &kn_lds[p5 * HH + j0]);
        vb[1] = v_lds[p1 * HH + i];  wb[1] = w_lds[p0 * VOC + p1];
        vb[2] = v_lds[p2 * HH + i];  wb[2] = w_lds[p1 * VOC + p2];
        vb[3] = v_lds[p3 * HH + i];  wb[3] = w_lds[p2 * VOC + p3];
        vb[4] = v_lds[p4 * HH + i];  wb[4] = w_lds[p3 * VOC + p4];
        vb[5] = v_lds[p5 * HH + i];  wb[5] = w_lds[p4 * VOC + p5];
        #pragma unroll
        for (int k = 0; k < 10; ++k) T[k] = seq_lds[5 + k];   // toks 5..14
    }
    float dP = v_lds[seq_lds[0] * HH + i];   // d_0 = v_0 (M_{-1} = 0)

    // ---- main loop: iters n = 0..2045 process steps 1..2046.
    // 255 groups of 8 + 6-iter tail.  Group g starts at n = 8g.
    for (int g = 0; g < 255; ++g) {
        // refill tokens for next group: toks 8g+15 .. 8g+22 (slack >= 8 iters)
        const int tb = 8 * g + 15;
        #pragma unroll
        for (int k = 0; k < 8; ++k) N[k] = seq_lds[tb + k];
        BODY(0) BODY(1) BODY(2) BODY(3) BODY(4) BODY(5) BODY(6) BODY(7)
        // shift queue: new T covers toks 8(g+1)+5 .. 8(g+1)+14
        T[0] = T[8]; T[1] = T[9];
        #pragma unroll
        for (int k = 0; k < 8; ++k) T[2 + k] = N[k];
    }
    BODY(0) BODY(1) BODY(2) BODY(3) BODY(4) BODY(5)   // n = 2040..2045

    // final pending update: M += d_2046 k_2046^T  (slot 2046&7 = 6)
    {
        f2 d2 = {dP, dP};
        #pragma unroll
        for (int m8 = 0; m8 < 8; ++m8) M2[m8] += d2 * Kb[6][m8];
    }

    // r_i = sum_j M[i][j] * q_j  with q = q_table[last token]
    {
        const int qtok = seq_lds[LSEQ - 1];
        const float* qrow = q_t + (long)qtok * HH + j0;
        f2 a0 = (f2){0.f, 0.f}, a1 = (f2){0.f, 0.f};
        #pragma unroll
        for (int n = 0; n < 4; ++n) {
            f2 q0 = (f2){qrow[2*n],     qrow[2*n + 1]};
            f2 q1 = (f2){qrow[2*n + 8], qrow[2*n + 9]};
            a0 += M2[n]     * q0;
            a1 += M2[n + 4] * q1;
        }
        f2 a = a0 + a1;
        float p = quad_sum(a[0] + a[1]);
        if ((tid & 3) == 0) r_lds[i] = p;
    }
    __syncthreads();

    // t = r @ wrp + brp
    if (tid < HH) {
        float s = brp[tid];
        #pragma unroll 8
        for (int ii = 0; ii < HH; ++ii) s = fmaf(r_lds[ii], wrp[ii * HH + tid], s);
        t_lds[tid] = s;
    }
    __syncthreads();

    // out = t @ wout + bout
    if (tid < HH) {
        float s = bout[tid];
        #pragma unroll 8
        for (int h = 0; h < HH; ++h) s = fmaf(t_lds[h], wout[h * VOC + tid], s);
        out[(long)b * VOC + tid] = s;
    }
}

extern "C" void kernel_launch(void* const* d_in, const int* in_sizes, int n_in,
                              void* d_out, int out_size, void* d_ws, size_t ws_size,
                              hipStream_t stream)
{
    const int*   seq   = (const int*)  d_in[0];
    const float* embed = (const float*)d_in[1];
    const float* w1    = (const float*)d_in[2];
    const float* b1    = (const float*)d_in[3];
    const float* w2    = (const float*)d_in[4];
    const float* b2    = (const float*)d_in[5];
    const float* ln_g  = (const float*)d_in[6];
    const float* ln_b  = (const float*)d_in[7];
    const float* wk    = (const float*)d_in[8];
    const float* wv    = (const float*)d_in[9];
    const float* wq    = (const float*)d_in[10];
    const float* wrp   = (const float*)d_in[11];
    const float* brp   = (const float*)d_in[12];
    const float* wout  = (const float*)d_in[13];
    const float* bout  = (const float*)d_in[14];
    float* out = (float*)d_out;

    float* kn_t = (float*)d_ws;
    float* v_t  = kn_t + VOC * HH;
    float* q_t  = v_t  + VOC * HH;
    float* w_t  = q_t  + VOC * HH;

    const int B = in_sizes[0] / LSEQ;   // 256

    hipLaunchKernelGGL(build_tables, dim3(VOC), dim3(H2), 0, stream,
                       embed, w1, b1, w2, b2, ln_g, ln_b, wk, wv, wq,
                       kn_t, v_t, q_t);
    hipLaunchKernelGGL(build_w, dim3(VOC), dim3(HH), 0, stream, kn_t, w_t);
    hipLaunchKernelGGL(delta_scan, dim3(B), dim3(256), 0, stream,
                       seq, kn_t, v_t, q_t, w_t, wrp, brp, wout, bout, out);
}